// Round 7
// baseline (174.580 us; speedup 1.0000x reference)
//
#include <hip/hip_runtime.h>
#include <math.h>

#define NN 512
#define MM 100
#define TPB 256
#define ROWS_OUT 8            // output rows per block strip
#define ROWS_LDS 18           // staged input-row window (8 + dy range ~10)
#define PLANES_PER_BLOCK 8
#define PXPT 16               // px per thread per plane = ROWS_OUT*NN/TPB

typedef float f32x4 __attribute__((ext_vector_type(4)));

// ws layout (floats): St[NN*MM] | B_u[MM*NN] | B_v[MM*NN] | dx[NN*NN] | dy[NN*NN]

__global__ void sin_table_kernel(float* __restrict__ St) {
    int tid = blockIdx.x * blockDim.x + threadIdx.x;
    if (tid >= NN * MM) return;
    int x = tid / MM, j = tid % MM;
    double arg = M_PI * ((double)x / (double)(NN - 1)) * (double)(j + 1);
    St[tid] = (float)sin(arg);
}

__global__ void bcoef_kernel(const float* __restrict__ St,
                             const float* __restrict__ c_u,
                             const float* __restrict__ c_v,
                             float* __restrict__ B_u,
                             float* __restrict__ B_v) {
    int x = blockIdx.x;
    int j = threadIdx.x;
    if (j >= MM) return;
    float au = 0.f, av = 0.f;
    for (int i = 0; i < MM; ++i) {
        int i1 = i + 1, j1 = j + 1;
        int r2i = i1 * i1 + j1 * j1;
        float w = (r2i <= 10100) ? (1.0f / sqrtf((float)r2i)) : 0.0f;
        float sw = St[x * MM + i] * w;
        au += sw * c_u[i * MM + j];
        av += sw * c_v[i * MM + j];
    }
    B_u[j * NN + x] = au;
    B_v[j * NN + x] = av;
}

// y-tiled: block computes 4 full rows; B_u/B_v read once per 4 rows
// (was: once per row-thread -> 512x redundancy, ~210 MB L2 traffic)
#define ROWS_F 4
__global__ __launch_bounds__(256)
void field_kernel(const float* __restrict__ St,
                  const float* __restrict__ B_u,
                  const float* __restrict__ B_v,
                  float scale,
                  float* __restrict__ dx,
                  float* __restrict__ dy) {
    __shared__ float sS[ROWS_F * MM];
    int t = threadIdx.x;
    int y0 = blockIdx.x * ROWS_F;

    for (int i = t; i < ROWS_F * MM; i += 256) {
        int r = i / MM, j = i % MM;
        sS[i] = St[(y0 + r) * MM + j];
    }
    __syncthreads();

    float au[ROWS_F][2] = {}, av[ROWS_F][2] = {};
    for (int j = 0; j < MM; ++j) {
        float bu0 = B_u[j * NN + t], bu1 = B_u[j * NN + t + 256];
        float bv0 = B_v[j * NN + t], bv1 = B_v[j * NN + t + 256];
        #pragma unroll
        for (int r = 0; r < ROWS_F; ++r) {
            float s = sS[r * MM + j];        // wave-uniform -> broadcast
            au[r][0] += bu0 * s; au[r][1] += bu1 * s;
            av[r][0] += bv0 * s; av[r][1] += bv1 * s;
        }
    }
    #pragma unroll
    for (int r = 0; r < ROWS_F; ++r) {
        int row = (y0 + r) * NN;
        dx[row + t]       = scale * au[r][0];
        dx[row + t + 256] = scale * au[r][1];
        dy[row + t]       = scale * av[r][0];
        dy[row + t + 256] = scale * av[r][1];
    }
}

__global__ __launch_bounds__(TPB, 4)
void remap_kernel(const float* __restrict__ img,
                  const float* __restrict__ dx,
                  const float* __restrict__ dy,
                  float* __restrict__ out,
                  int planes) {
    // 18*512+1 floats = 36,868 B -> 4 blocks/CU capacity (grid gives 3/CU).
    // TA-bound regime: halo amplification (staged/output rows = 18/8 vs 13/4)
    // is what matters, not occupancy (R5/R6 evidence).
    __shared__ __align__(16) float rows[ROWS_LDS * NN + 1];
    __shared__ int s_mn[4], s_mx[4];
    __shared__ int s_r0, s_nr;

    // XCD-bijective swizzle (gridDim.x % 8 == 0). Confirmed FETCH 182->61 MB.
    int nb = gridDim.x;
    int bid = blockIdx.x;
    int sid = (bid & 7) * (nb >> 3) + (bid >> 3);
    int strip = sid & 63;        // 64 strips per plane (512/8)
    int pg    = sid >> 6;        // plane group

    int t = threadIdx.x;
    int Y = strip * ROWS_OUT;

    // --- per-pixel precompute (once; reused across 8 planes) ---
    float w00[PXPT], w01[PXPT], w10[PXPT], w11[PXPT];
    int offA[PXPT], offB[PXPT];
    int myf = NN, Myc = -1;
    #pragma unroll
    for (int i = 0; i < PXPT; ++i) {
        int xi = ((i & 1) << 8) + t;
        int yi = Y + (i >> 1);
        int pix = (yi << 9) + xi;
        float xn = fminf(fmaxf((float)xi - dx[pix], 0.0f), (float)(NN - 1));
        float yn = fminf(fmaxf((float)yi - dy[pix], 0.0f), (float)(NN - 1));
        int xf = (int)floorf(xn), yf = (int)floorf(yn);
        int yc = (int)ceilf(yn);
        float xv = xn - (float)xf, yv = yn - (float)yf;
        w00[i] = (1.f - yv) * (1.f - xv);
        w01[i] = (1.f - yv) * xv;
        w10[i] = yv * (1.f - xv);
        w11[i] = yv * xv;
        offA[i] = (yf << 9) + xf;
        offB[i] = (yc << 9) + xf;
        myf = min(myf, yf);
        Myc = max(Myc, yc);
    }

    for (int d = 32; d; d >>= 1) {
        myf = min(myf, __shfl_xor(myf, d));
        Myc = max(Myc, __shfl_xor(Myc, d));
    }
    int wid = t >> 6;
    if ((t & 63) == 0) { s_mn[wid] = myf; s_mx[wid] = Myc; }
    __syncthreads();
    if (t == 0) {
        int a = min(min(s_mn[0], s_mn[1]), min(s_mn[2], s_mn[3]));
        int b = max(max(s_mx[0], s_mx[1]), max(s_mx[2], s_mx[3]));
        s_r0 = a; s_nr = b - a + 1;
        // pad slot read only with weight exactly 0 (xf==511 -> w01=w11=0)
        rows[(b - a + 1) * NN] = 0.f;
    }
    __syncthreads();
    int r0 = s_r0, nr = s_nr;

    int p0 = pg * PLANES_PER_BLOCK;
    int p1 = p0 + PLANES_PER_BLOCK; if (p1 > planes) p1 = planes;

    if (nr <= ROWS_LDS) {
        int rb = r0 << 9;
        #pragma unroll
        for (int i = 0; i < PXPT; ++i) { offA[i] -= rb; offB[i] -= rb; }

        int nbytes = nr << 11;   // nr * 512 * 4
        for (int p = p0; p < p1; ++p) {
            const char* ip = (const char*)(img + (size_t)p * (NN * NN) + rb);
            for (int off = t * 16; off < nbytes; off += TPB * 16) {
                *(f32x4*)((char*)rows + off) = *(const f32x4*)(ip + off);
            }
            __syncthreads();
            float* op = out + (size_t)p * (NN * NN);
            #pragma unroll
            for (int i = 0; i < PXPT; ++i) {
                float a0 = rows[offA[i]];
                float a1 = rows[offA[i] + 1];
                float b0 = rows[offB[i]];
                float b1 = rows[offB[i] + 1];
                float o = w00[i] * a0 + w01[i] * a1 + w10[i] * b0 + w11[i] * b1;
                int xi = ((i & 1) << 8) + t;
                int yi = Y + (i >> 1);
                __builtin_nontemporal_store(o, op + (yi << 9) + xi);
            }
            __syncthreads();
        }
    } else {
        // fallback: direct global gathers, same math (correct for any dy)
        for (int p = p0; p < p1; ++p) {
            const float* __restrict__ ip = img + (size_t)p * (NN * NN);
            float* op = out + (size_t)p * (NN * NN);
            #pragma unroll
            for (int i = 0; i < PXPT; ++i) {
                int e1 = ((offA[i] & 511) == 511) ? 0 : 1;
                float a0 = ip[offA[i]], a1 = ip[offA[i] + e1];
                float b0 = ip[offB[i]], b1 = ip[offB[i] + e1];
                float o = w00[i] * a0 + w01[i] * a1 + w10[i] * b0 + w11[i] * b1;
                int xi = ((i & 1) << 8) + t;
                int yi = Y + (i >> 1);
                __builtin_nontemporal_store(o, op + (yi << 9) + xi);
            }
        }
    }
}

extern "C" void kernel_launch(void* const* d_in, const int* in_sizes, int n_in,
                              void* d_out, int out_size, void* d_ws, size_t ws_size,
                              hipStream_t stream) {
    const float* img = (const float*)d_in[0];
    const float* c_u = (const float*)d_in[1];
    const float* c_v = (const float*)d_in[2];
    float* out = (float*)d_out;

    int planes = in_sizes[0] / (NN * NN);   // 96

    float* ws  = (float*)d_ws;
    float* St  = ws;
    float* B_u = St  + NN * MM;
    float* B_v = B_u + MM * NN;
    float* dx  = B_v + MM * NN;
    float* dy  = dx  + NN * NN;

    double log_cut = log((double)MM + 1e-6);
    double T1 = 1.0 / (M_PI * (double)NN * (double)NN * log_cut);
    double T2 = 4.0 / (M_PI * M_PI * M_PI * (double)MM * (double)MM * log_cut);
    if (T2 < T1) T2 = T1;
    double T = 0.5 * (T1 + T2);
    float scale = (float)(sqrt(T) * (double)NN);

    sin_table_kernel<<<(NN * MM + 255) / 256, 256, 0, stream>>>(St);
    bcoef_kernel<<<NN, 128, 0, stream>>>(St, c_u, c_v, B_u, B_v);
    field_kernel<<<NN / ROWS_F, 256, 0, stream>>>(St, B_u, B_v, scale, dx, dy);

    int strips = NN / ROWS_OUT;                                      // 64
    int groups = (planes + PLANES_PER_BLOCK - 1) / PLANES_PER_BLOCK; // 12
    remap_kernel<<<strips * groups, TPB, 0, stream>>>(img, dx, dy, out, planes);
}

// Round 8
// 80.385 us; speedup vs baseline: 2.1718x; 2.1718x over previous
//
#include <hip/hip_runtime.h>
#include <math.h>

#define NN 512
#define MM 100
#define TPB 256
#define ROWS_OUT 4            // output rows per block strip (R6 sweet spot)
#define ROWS_LDS 13           // staged input-row window
#define PLANES_PER_BLOCK 8
#define PXPT 8                // px per thread per plane

typedef float f32x4 __attribute__((ext_vector_type(4)));

// ws layout (floats): St[NN*MM] | B_u[MM*NN] | B_v[MM*NN] | dx[NN*NN] | dy[NN*NN]

__global__ void sin_table_kernel(float* __restrict__ St) {
    int tid = blockIdx.x * blockDim.x + threadIdx.x;
    if (tid >= NN * MM) return;
    int x = tid / MM, j = tid % MM;
    double arg = M_PI * ((double)x / (double)(NN - 1)) * (double)(j + 1);
    St[tid] = (float)sin(arg);
}

__global__ void bcoef_kernel(const float* __restrict__ St,
                             const float* __restrict__ c_u,
                             const float* __restrict__ c_v,
                             float* __restrict__ B_u,
                             float* __restrict__ B_v) {
    int x = blockIdx.x;
    int j = threadIdx.x;
    if (j >= MM) return;
    float au = 0.f, av = 0.f;
    for (int i = 0; i < MM; ++i) {
        int i1 = i + 1, j1 = j + 1;
        int r2i = i1 * i1 + j1 * j1;
        float w = (r2i <= 10100) ? (1.0f / sqrtf((float)r2i)) : 0.0f;
        float sw = St[x * MM + i] * w;
        au += sw * c_u[i * MM + j];
        av += sw * c_v[i * MM + j];
    }
    B_u[j * NN + x] = au;
    B_v[j * NN + x] = av;
}

// y-tiled: block computes 4 full rows; B_u/B_v traffic /128 (confirmed win R7:
// non-remap time 16 -> 9.4 us)
#define ROWS_F 4
__global__ __launch_bounds__(256)
void field_kernel(const float* __restrict__ St,
                  const float* __restrict__ B_u,
                  const float* __restrict__ B_v,
                  float scale,
                  float* __restrict__ dx,
                  float* __restrict__ dy) {
    __shared__ float sS[ROWS_F * MM];
    int t = threadIdx.x;
    int y0 = blockIdx.x * ROWS_F;

    for (int i = t; i < ROWS_F * MM; i += 256) {
        int r = i / MM, j = i % MM;
        sS[i] = St[(y0 + r) * MM + j];
    }
    __syncthreads();

    float au[ROWS_F][2] = {}, av[ROWS_F][2] = {};
    for (int j = 0; j < MM; ++j) {
        float bu0 = B_u[j * NN + t], bu1 = B_u[j * NN + t + 256];
        float bv0 = B_v[j * NN + t], bv1 = B_v[j * NN + t + 256];
        #pragma unroll
        for (int r = 0; r < ROWS_F; ++r) {
            float s = sS[r * MM + j];
            au[r][0] += bu0 * s; au[r][1] += bu1 * s;
            av[r][0] += bv0 * s; av[r][1] += bv1 * s;
        }
    }
    #pragma unroll
    for (int r = 0; r < ROWS_F; ++r) {
        int row = (y0 + r) * NN;
        dx[row + t]       = scale * au[r][0];
        dx[row + t + 256] = scale * au[r][1];
        dy[row + t]       = scale * av[r][0];
        dy[row + t + 256] = scale * av[r][1];
    }
}

__global__ __launch_bounds__(TPB, 6)
void remap_kernel(const float* __restrict__ img,
                  const float* __restrict__ dx,
                  const float* __restrict__ dy,
                  float* __restrict__ out,
                  int planes) {
    // 13*512+1 floats = 26.6 KB -> 6 blocks/CU (R6-measured 58% occupancy).
    __shared__ __align__(16) float rows[ROWS_LDS * NN + 1];
    __shared__ int s_mn[4], s_mx[4];
    __shared__ int s_r0, s_nr;

    // XCD-bijective swizzle (gridDim.x % 8 == 0). Confirmed FETCH 182->61 MB.
    int nb = gridDim.x;
    int bid = blockIdx.x;
    int sid = (bid & 7) * (nb >> 3) + (bid >> 3);
    int strip = sid & 127;       // 128 strips per plane (512/4)
    int pg    = sid >> 7;        // plane group

    int t = threadIdx.x;
    int Y = strip * ROWS_OUT;

    // --- per-pixel precompute (once; reused across 8 planes) ---
    float w00[PXPT], w01[PXPT], w10[PXPT], w11[PXPT];
    int offA[PXPT], offB[PXPT];
    int myf = NN, Myc = -1;
    #pragma unroll
    for (int i = 0; i < PXPT; ++i) {
        int xi = ((i & 1) << 8) + t;
        int yi = Y + (i >> 1);
        int pix = (yi << 9) + xi;
        float xn = fminf(fmaxf((float)xi - dx[pix], 0.0f), (float)(NN - 1));
        float yn = fminf(fmaxf((float)yi - dy[pix], 0.0f), (float)(NN - 1));
        int xf = (int)floorf(xn), yf = (int)floorf(yn);
        int yc = (int)ceilf(yn);
        float xv = xn - (float)xf, yv = yn - (float)yf;
        w00[i] = (1.f - yv) * (1.f - xv);
        w01[i] = (1.f - yv) * xv;
        w10[i] = yv * (1.f - xv);
        w11[i] = yv * xv;
        offA[i] = (yf << 9) + xf;
        offB[i] = (yc << 9) + xf;
        myf = min(myf, yf);
        Myc = max(Myc, yc);
    }

    for (int d = 32; d; d >>= 1) {
        myf = min(myf, __shfl_xor(myf, d));
        Myc = max(Myc, __shfl_xor(Myc, d));
    }
    int wid = t >> 6;
    if ((t & 63) == 0) { s_mn[wid] = myf; s_mx[wid] = Myc; }
    __syncthreads();
    if (t == 0) {
        int a = min(min(s_mn[0], s_mn[1]), min(s_mn[2], s_mn[3]));
        int b = max(max(s_mx[0], s_mx[1]), max(s_mx[2], s_mx[3]));
        s_r0 = a; s_nr = b - a + 1;
        // pad slot: read only with weight exactly 0 (xf==511 -> w01=w11=0);
        // staging writes < nr*NN, never touches it
        rows[(b - a + 1) * NN] = 0.f;
    }
    __syncthreads();
    int r0 = s_r0, nr = s_nr;

    int p0 = pg * PLANES_PER_BLOCK;
    int p1 = p0 + PLANES_PER_BLOCK; if (p1 > planes) p1 = planes;

    if (nr <= ROWS_LDS) {
        int rb = r0 << 9;
        #pragma unroll
        for (int i = 0; i < PXPT; ++i) { offA[i] -= rb; offB[i] -= rb; }

        int nbytes = nr << 11;                  // nr*512*4, multiple of 2048
        int wave = t >> 6;
        int lane_goff = t * 16;                 // = wave*1024 + lane*16
        for (int p = p0; p < p1; ++p) {
            const char* ip = (const char*)(img + (size_t)p * (NN * NN) + rb);
            // HBM -> LDS DMA staging: no ds_write instrs, no staging VGPRs.
            // LDS dest per wave is uniform base; HW adds lane*16.
            for (int ob = 0; ob < nbytes; ob += TPB * 16) {
                if (ob + wave * 1024 < nbytes) {
                    __builtin_amdgcn_global_load_lds(
                        (const __attribute__((address_space(1))) void*)(ip + ob + lane_goff),
                        (__attribute__((address_space(3))) void*)((char*)rows + ob + wave * 1024),
                        16, 0, 0);
                }
            }
            __syncthreads();   // compiler drains vmcnt before s_barrier
            float* op = out + (size_t)p * (NN * NN);
            #pragma unroll
            for (int i = 0; i < PXPT; ++i) {
                float a0 = rows[offA[i]];
                float a1 = rows[offA[i] + 1];   // adjacent -> ds_read2_b32
                float b0 = rows[offB[i]];
                float b1 = rows[offB[i] + 1];
                float o = w00[i] * a0 + w01[i] * a1 + w10[i] * b0 + w11[i] * b1;
                int xi = ((i & 1) << 8) + t;
                int yi = Y + (i >> 1);
                __builtin_nontemporal_store(o, op + (yi << 9) + xi);
            }
            __syncthreads();
        }
    } else {
        // fallback: direct global gathers, same math (correct for any dy)
        for (int p = p0; p < p1; ++p) {
            const float* __restrict__ ip = img + (size_t)p * (NN * NN);
            float* op = out + (size_t)p * (NN * NN);
            #pragma unroll
            for (int i = 0; i < PXPT; ++i) {
                int e1 = ((offA[i] & 511) == 511) ? 0 : 1;
                float a0 = ip[offA[i]], a1 = ip[offA[i] + e1];
                float b0 = ip[offB[i]], b1 = ip[offB[i] + e1];
                float o = w00[i] * a0 + w01[i] * a1 + w10[i] * b0 + w11[i] * b1;
                int xi = ((i & 1) << 8) + t;
                int yi = Y + (i >> 1);
                __builtin_nontemporal_store(o, op + (yi << 9) + xi);
            }
        }
    }
}

extern "C" void kernel_launch(void* const* d_in, const int* in_sizes, int n_in,
                              void* d_out, int out_size, void* d_ws, size_t ws_size,
                              hipStream_t stream) {
    const float* img = (const float*)d_in[0];
    const float* c_u = (const float*)d_in[1];
    const float* c_v = (const float*)d_in[2];
    float* out = (float*)d_out;

    int planes = in_sizes[0] / (NN * NN);   // 96

    float* ws  = (float*)d_ws;
    float* St  = ws;
    float* B_u = St  + NN * MM;
    float* B_v = B_u + MM * NN;
    float* dx  = B_v + MM * NN;
    float* dy  = dx  + NN * NN;

    double log_cut = log((double)MM + 1e-6);
    double T1 = 1.0 / (M_PI * (double)NN * (double)NN * log_cut);
    double T2 = 4.0 / (M_PI * M_PI * M_PI * (double)MM * (double)MM * log_cut);
    if (T2 < T1) T2 = T1;
    double T = 0.5 * (T1 + T2);
    float scale = (float)(sqrt(T) * (double)NN);

    sin_table_kernel<<<(NN * MM + 255) / 256, 256, 0, stream>>>(St);
    bcoef_kernel<<<NN, 128, 0, stream>>>(St, c_u, c_v, B_u, B_v);
    field_kernel<<<NN / ROWS_F, 256, 0, stream>>>(St, B_u, B_v, scale, dx, dy);

    int strips = NN / ROWS_OUT;                                      // 128
    int groups = (planes + PLANES_PER_BLOCK - 1) / PLANES_PER_BLOCK; // 12
    remap_kernel<<<strips * groups, TPB, 0, stream>>>(img, dx, dy, out, planes);
}

// Round 9
// 80.098 us; speedup vs baseline: 2.1796x; 1.0036x over previous
//
#include <hip/hip_runtime.h>
#include <math.h>

#define NN 512
#define MM 100
#define TPB 256
#define ROWS_OUT 4            // output rows per block strip
#define ROWS_LDS 13           // staged input-row window
#define PXPT 8                // px per thread per plane

typedef float f32x4 __attribute__((ext_vector_type(4)));

// ws layout (floats): St[NN*MM] | B_u[MM*NN] | B_v[MM*NN] | dx[NN*NN] | dy[NN*NN]

__global__ void sin_table_kernel(float* __restrict__ St) {
    int tid = blockIdx.x * blockDim.x + threadIdx.x;
    if (tid >= NN * MM) return;
    int x = tid / MM, j = tid % MM;
    double arg = M_PI * ((double)x / (double)(NN - 1)) * (double)(j + 1);
    St[tid] = (float)sin(arg);
}

__global__ void bcoef_kernel(const float* __restrict__ St,
                             const float* __restrict__ c_u,
                             const float* __restrict__ c_v,
                             float* __restrict__ B_u,
                             float* __restrict__ B_v) {
    int x = blockIdx.x;
    int j = threadIdx.x;
    if (j >= MM) return;
    float au = 0.f, av = 0.f;
    for (int i = 0; i < MM; ++i) {
        int i1 = i + 1, j1 = j + 1;
        int r2i = i1 * i1 + j1 * j1;
        float w = (r2i <= 10100) ? (1.0f / sqrtf((float)r2i)) : 0.0f;
        float sw = St[x * MM + i] * w;
        au += sw * c_u[i * MM + j];
        av += sw * c_v[i * MM + j];
    }
    B_u[j * NN + x] = au;
    B_v[j * NN + x] = av;
}

// y-tiled: block computes 4 full rows; B_u/B_v traffic /128 (confirmed win)
#define ROWS_F 4
__global__ __launch_bounds__(256)
void field_kernel(const float* __restrict__ St,
                  const float* __restrict__ B_u,
                  const float* __restrict__ B_v,
                  float scale,
                  float* __restrict__ dx,
                  float* __restrict__ dy) {
    __shared__ float sS[ROWS_F * MM];
    int t = threadIdx.x;
    int y0 = blockIdx.x * ROWS_F;

    for (int i = t; i < ROWS_F * MM; i += 256) {
        int r = i / MM, j = i % MM;
        sS[i] = St[(y0 + r) * MM + j];
    }
    __syncthreads();

    float au[ROWS_F][2] = {}, av[ROWS_F][2] = {};
    for (int j = 0; j < MM; ++j) {
        float bu0 = B_u[j * NN + t], bu1 = B_u[j * NN + t + 256];
        float bv0 = B_v[j * NN + t], bv1 = B_v[j * NN + t + 256];
        #pragma unroll
        for (int r = 0; r < ROWS_F; ++r) {
            float s = sS[r * MM + j];
            au[r][0] += bu0 * s; au[r][1] += bu1 * s;
            av[r][0] += bv0 * s; av[r][1] += bv1 * s;
        }
    }
    #pragma unroll
    for (int r = 0; r < ROWS_F; ++r) {
        int row = (y0 + r) * NN;
        dx[row + t]       = scale * au[r][0];
        dx[row + t + 256] = scale * au[r][1];
        dy[row + t]       = scale * av[r][0];
        dy[row + t + 256] = scale * av[r][1];
    }
}

// One plane per block: stage -> ONE drain barrier -> compute -> exit.
// No serialized multi-plane chain; DMA latency hidden by 6 independent
// blocks/CU (R8 evidence: barrier-drain serialization was the residual).
__global__ __launch_bounds__(TPB, 6)
void remap_kernel(const float* __restrict__ img,
                  const float* __restrict__ dx,
                  const float* __restrict__ dy,
                  float* __restrict__ out,
                  int planes) {
    __shared__ __align__(16) float rows[ROWS_LDS * NN + 1];
    __shared__ int s_mn[4], s_mx[4];

    // XCD-bijective swizzle (gridDim.x % 8 == 0), plane-major: adjacent
    // strips (sharing halo rows) adjacent on the same XCD; dx/dy (2 MB)
    // L2-resident per XCD.
    int nb = gridDim.x;
    int bid = blockIdx.x;
    int sid = (bid & 7) * (nb >> 3) + (bid >> 3);
    int plane = sid >> 7;        // 128 strips per plane (512/4)
    int strip = sid & 127;

    int t = threadIdx.x;
    int Y = strip * ROWS_OUT;

    // --- per-pixel precompute ---
    float w00[PXPT], w01[PXPT], w10[PXPT], w11[PXPT];
    int offA[PXPT], offB[PXPT];
    int myf = NN, Myc = -1;
    #pragma unroll
    for (int i = 0; i < PXPT; ++i) {
        int xi = ((i & 1) << 8) + t;
        int yi = Y + (i >> 1);
        int pix = (yi << 9) + xi;
        float xn = fminf(fmaxf((float)xi - dx[pix], 0.0f), (float)(NN - 1));
        float yn = fminf(fmaxf((float)yi - dy[pix], 0.0f), (float)(NN - 1));
        int xf = (int)floorf(xn), yf = (int)floorf(yn);
        int yc = (int)ceilf(yn);
        float xv = xn - (float)xf, yv = yn - (float)yf;
        w00[i] = (1.f - yv) * (1.f - xv);
        w01[i] = (1.f - yv) * xv;
        w10[i] = yv * (1.f - xv);
        w11[i] = yv * xv;
        offA[i] = (yf << 9) + xf;
        offB[i] = (yc << 9) + xf;
        myf = min(myf, yf);
        Myc = max(Myc, yc);
    }

    for (int d = 32; d; d >>= 1) {
        myf = min(myf, __shfl_xor(myf, d));
        Myc = max(Myc, __shfl_xor(Myc, d));
    }
    int wid = t >> 6;
    if ((t & 63) == 0) { s_mn[wid] = myf; s_mx[wid] = Myc; }
    __syncthreads();
    int r0 = min(min(s_mn[0], s_mn[1]), min(s_mn[2], s_mn[3]));
    int nr = max(max(s_mx[0], s_mx[1]), max(s_mx[2], s_mx[3])) - r0 + 1;

    const float* __restrict__ ip = img + (size_t)plane * (NN * NN);
    float* __restrict__ op = out + (size_t)plane * (NN * NN);

    if (nr <= ROWS_LDS) {
        int rb = r0 << 9;
        #pragma unroll
        for (int i = 0; i < PXPT; ++i) { offA[i] -= rb; offB[i] -= rb; }

        // pad slot: read only with weight exactly 0 (xf==511 -> w01=w11=0);
        // DMA writes [0, nr*NN) floats, never touches it
        if (t == 0) rows[nr * NN] = 0.f;

        int nbytes = nr << 11;                  // nr*512*4
        int wave = t >> 6;
        int lane_goff = t * 16;                 // = wave*1024 + lane*16
        const char* ipc = (const char*)ip + (rb << 2);
        // HBM -> LDS DMA staging: no ds_write instrs, no staging VGPRs
        for (int ob = 0; ob < nbytes; ob += TPB * 16) {
            if (ob + wave * 1024 < nbytes) {
                __builtin_amdgcn_global_load_lds(
                    (const __attribute__((address_space(1))) void*)(ipc + ob + lane_goff),
                    (__attribute__((address_space(3))) void*)((char*)rows + ob + wave * 1024),
                    16, 0, 0);
            }
        }
        __syncthreads();   // single drain; block exits after compute

        #pragma unroll
        for (int i = 0; i < PXPT; ++i) {
            float a0 = rows[offA[i]];
            float a1 = rows[offA[i] + 1];
            float b0 = rows[offB[i]];
            float b1 = rows[offB[i] + 1];
            float o = w00[i] * a0 + w01[i] * a1 + w10[i] * b0 + w11[i] * b1;
            int xi = ((i & 1) << 8) + t;
            int yi = Y + (i >> 1);
            __builtin_nontemporal_store(o, op + (yi << 9) + xi);
        }
    } else {
        // fallback: direct global gathers, same math (correct for any dy)
        #pragma unroll
        for (int i = 0; i < PXPT; ++i) {
            int e1 = ((offA[i] & 511) == 511) ? 0 : 1;
            float a0 = ip[offA[i]], a1 = ip[offA[i] + e1];
            float b0 = ip[offB[i]], b1 = ip[offB[i] + e1];
            float o = w00[i] * a0 + w01[i] * a1 + w10[i] * b0 + w11[i] * b1;
            int xi = ((i & 1) << 8) + t;
            int yi = Y + (i >> 1);
            __builtin_nontemporal_store(o, op + (yi << 9) + xi);
        }
    }
}

extern "C" void kernel_launch(void* const* d_in, const int* in_sizes, int n_in,
                              void* d_out, int out_size, void* d_ws, size_t ws_size,
                              hipStream_t stream) {
    const float* img = (const float*)d_in[0];
    const float* c_u = (const float*)d_in[1];
    const float* c_v = (const float*)d_in[2];
    float* out = (float*)d_out;

    int planes = in_sizes[0] / (NN * NN);   // 96

    float* ws  = (float*)d_ws;
    float* St  = ws;
    float* B_u = St  + NN * MM;
    float* B_v = B_u + MM * NN;
    float* dx  = B_v + MM * NN;
    float* dy  = dx  + NN * NN;

    double log_cut = log((double)MM + 1e-6);
    double T1 = 1.0 / (M_PI * (double)NN * (double)NN * log_cut);
    double T2 = 4.0 / (M_PI * M_PI * M_PI * (double)MM * (double)MM * log_cut);
    if (T2 < T1) T2 = T1;
    double T = 0.5 * (T1 + T2);
    float scale = (float)(sqrt(T) * (double)NN);

    sin_table_kernel<<<(NN * MM + 255) / 256, 256, 0, stream>>>(St);
    bcoef_kernel<<<NN, 128, 0, stream>>>(St, c_u, c_v, B_u, B_v);
    field_kernel<<<NN / ROWS_F, 256, 0, stream>>>(St, B_u, B_v, scale, dx, dy);

    int strips = NN / ROWS_OUT;                  // 128
    remap_kernel<<<strips * planes, TPB, 0, stream>>>(img, dx, dy, out, planes);
}